// Round 1
// baseline (1089.271 us; speedup 1.0000x reference)
//
#include <hip/hip_runtime.h>
#include <math.h>

// FastFourierConvolution: B=4, C=128, H=W=256. Cg=Cl=64, Ci=32.
// FU1: (B,32,256,256) -> rfft2 -> conv64x64+BN+relu -> herm irfft2
// FU2 (LFU): y_in[:,24:32] quadrant-stacked to (B,32,128,128), same pipeline, tiled 2x2.

#define PI2 6.283185307179586f

// ---------------- FFT core: radix-2 DIT in LDS, blockDim == N/2 ----------------
template<int N, int LOG2N>
__device__ __forceinline__ void fft_stages(float* re, float* im, int tid, float sign) {
#pragma unroll
  for (int s = 1; s <= LOG2N; ++s) {
    __syncthreads();
    const int half = 1 << (s - 1);
    const int j = tid & (half - 1);
    const int i1 = ((tid >> (s - 1)) << s) + j;
    const int i2 = i1 + half;
    float ang = sign * (PI2 / (float)(1 << s)) * (float)j;
    float wr, wi;
    __sincosf(ang, &wi, &wr);
    float xr = re[i2], xi = im[i2];
    float vr = xr * wr - xi * wi;
    float vi = xr * wi + xi * wr;
    float ur = re[i1], ui = im[i1];
    re[i1] = ur + vr; im[i1] = ui + vi;
    re[i2] = ur - vr; im[i2] = ui - vi;
  }
  __syncthreads();
}

// row rfft: one block per row of length N (real) -> N/2+1 complex bins
template<int N, int LOG2N>
__global__ void rfft_rows(const float* __restrict__ src, float2* __restrict__ dst) {
  __shared__ float re[N], im[N];
  const int row = blockIdx.x;
  const int tid = threadIdx.x;  // N/2 threads
  const float* p = src + (size_t)row * N;
  for (int i = tid; i < N; i += N / 2) {
    int j = __brev((unsigned)i) >> (32 - LOG2N);
    re[j] = p[i];
    im[j] = 0.f;
  }
  fft_stages<N, LOG2N>(re, im, tid, -1.f);
  float2* q = dst + (size_t)row * (N / 2 + 1);
  for (int k = tid; k <= N / 2; k += N / 2) q[k] = make_float2(re[k], im[k]);
}

// LFU gather + row rfft (N=128): reads quadrants of y_in channels 24..31
__global__ void rfft_rows_lfu(const float* __restrict__ y_in, float2* __restrict__ dst) {
  __shared__ float re[128], im[128];
  const int bid = blockIdx.x;          // ((b*32+c2)*128 + h2)
  const int h2 = bid & 127;
  const int c2 = (bid >> 7) & 31;
  const int b  = bid >> 12;
  const int q = c2 >> 3, ch = c2 & 7;
  const int hs = ((q >> 1) << 7) + h2;
  const int ws0 = (q & 1) << 7;
  const float* p = y_in + (((size_t)(b * 32 + 24 + ch) * 256 + hs) * 256 + ws0);
  const int tid = threadIdx.x;  // 64
  for (int i = tid; i < 128; i += 64) {
    int j = __brev((unsigned)i) >> 25;
    re[j] = p[i];
    im[j] = 0.f;
  }
  fft_stages<128, 7>(re, im, tid, -1.f);
  float2* qp = dst + (size_t)bid * 65;
  for (int k = tid; k <= 64; k += 64) qp[k] = make_float2(re[k], im[k]);
}

// column FFT (complex, in-place), H == N; one block per (img,k)
template<int N, int LOG2N>
__global__ void cfft_cols(float2* __restrict__ data, int Wf, float sign) {
  __shared__ float re[N], im[N];
  const int img = blockIdx.x / Wf;
  const int k = blockIdx.x % Wf;
  float2* base = data + (size_t)img * N * Wf + k;
  const int tid = threadIdx.x;  // N/2
  for (int i = tid; i < N; i += N / 2) {
    float2 v = base[(size_t)i * Wf];
    int j = __brev((unsigned)i) >> (32 - LOG2N);
    re[j] = v.x; im[j] = v.y;
  }
  fft_stages<N, LOG2N>(re, im, tid, sign);
  for (int i = tid; i < N; i += N / 2) base[(size_t)i * Wf] = make_float2(re[i], im[i]);
}

// row irfft: Hermitian-extend N/2+1 bins to N, inverse FFT, keep real*scale
template<int N, int LOG2N>
__global__ void irfft_rows(const float2* __restrict__ T, float* __restrict__ out, float scale) {
  __shared__ float re[N], im[N];
  const int row = blockIdx.x;
  const float2* p = T + (size_t)row * (N / 2 + 1);
  const int tid = threadIdx.x;  // N/2
  for (int i = tid; i < N; i += N / 2) {
    float2 v;
    if (i <= N / 2) v = p[i];
    else { v = p[N - i]; v.y = -v.y; }
    int j = __brev((unsigned)i) >> (32 - LOG2N);
    re[j] = v.x; im[j] = v.y;
  }
  fft_stages<N, LOG2N>(re, im, tid, 1.f);
  float* q = out + (size_t)row * N;
  for (int i = tid; i < N; i += N / 2) q[i] = re[i] * scale;
}

// ---------------- y_in = w_in(32x64) @ x[:, :64] + b_in ----------------
__global__ void conv_in(const float* __restrict__ x, const float* __restrict__ w,
                        const float* __restrict__ bias, float* __restrict__ y) {
  __shared__ float wt[32 * 64];  // transposed: wt[ci*32+o]
  __shared__ float bl[32];
  const int t = threadIdx.x;
  for (int idx = t; idx < 2048; idx += 256) wt[idx] = w[(idx & 31) * 64 + (idx >> 5)];
  if (t < 32) bl[t] = bias[t];
  __syncthreads();
  const int p = blockIdx.x * 256 + t;   // B*H*W = 262144
  const int hw = p & 65535;
  const int b = p >> 16;
  float acc[32];
#pragma unroll
  for (int o = 0; o < 32; ++o) acc[o] = bl[o];
  const float* xb = x + (size_t)b * 128 * 65536 + hw;
  for (int ci = 0; ci < 64; ++ci) {
    float v = xb[(size_t)ci * 65536];
    const float4* w4 = (const float4*)&wt[ci * 32];
#pragma unroll
    for (int o4 = 0; o4 < 8; ++o4) {
      float4 a = w4[o4];
      acc[4 * o4 + 0] += a.x * v;
      acc[4 * o4 + 1] += a.y * v;
      acc[4 * o4 + 2] += a.z * v;
      acc[4 * o4 + 3] += a.w * v;
    }
  }
  float* yb = y + (size_t)b * 32 * 65536 + hw;
#pragma unroll
  for (int o = 0; o < 32; ++o) yb[(size_t)o * 65536] = acc[o];
}

// ---------------- spectral conv: Z[co](b,h,k) = w(64x64) @ [Re;Im] + b ----------------
template<int B_, int H_, int Wf_>
__global__ void conv_spec(const float2* __restrict__ S, const float* __restrict__ w,
                          const float* __restrict__ bias, float* __restrict__ Z) {
  __shared__ float wt[64 * 64];  // transposed: wt[ci*64+co]
  __shared__ float bl[64];
  const int t = threadIdx.x;
  for (int idx = t; idx < 4096; idx += 256) wt[idx] = w[(idx & 63) * 64 + (idx >> 6)];
  if (t < 64) bl[t] = bias[t];
  __syncthreads();
  const int p = blockIdx.x * 256 + t;  // B_*H_*Wf_
  const int k = p % Wf_;
  const int h = (p / Wf_) % H_;
  const int b = p / (Wf_ * H_);
  float acc[64];
#pragma unroll
  for (int o = 0; o < 64; ++o) acc[o] = bl[o];
  for (int ci = 0; ci < 32; ++ci) {
    float2 s = S[((size_t)(b * 32 + ci) * H_ + h) * Wf_ + k];
    const float4* wr4 = (const float4*)&wt[ci * 64];
    const float4* wi4 = (const float4*)&wt[(ci + 32) * 64];
#pragma unroll
    for (int o4 = 0; o4 < 16; ++o4) {
      float4 a = wr4[o4], c = wi4[o4];
      acc[4 * o4 + 0] += a.x * s.x + c.x * s.y;
      acc[4 * o4 + 1] += a.y * s.x + c.y * s.y;
      acc[4 * o4 + 2] += a.z * s.x + c.z * s.y;
      acc[4 * o4 + 3] += a.w * s.x + c.w * s.y;
    }
  }
  const size_t chs = (size_t)B_ * H_ * Wf_;
  const size_t pix = ((size_t)b * H_ + h) * Wf_ + k;
#pragma unroll
  for (int o = 0; o < 64; ++o) Z[o * chs + pix] = acc[o];
}

// ---------------- BN stats per channel (64 blocks) ----------------
__global__ void bn_stats(const float* __restrict__ Z, int n,
                         const float* __restrict__ gamma, const float* __restrict__ beta,
                         float* __restrict__ scale, float* __restrict__ shift) {
  const int c = blockIdx.x;
  const float* p = Z + (size_t)c * n;
  double s = 0.0, s2 = 0.0;
  for (int i = threadIdx.x; i < n; i += 256) {
    float v = p[i];
    s += v;
    s2 += (double)v * (double)v;
  }
  __shared__ double sh[256], sh2[256];
  sh[threadIdx.x] = s; sh2[threadIdx.x] = s2;
  __syncthreads();
  for (int off = 128; off > 0; off >>= 1) {
    if (threadIdx.x < off) { sh[threadIdx.x] += sh[threadIdx.x + off]; sh2[threadIdx.x] += sh2[threadIdx.x + off]; }
    __syncthreads();
  }
  if (threadIdx.x == 0) {
    double mu = sh[0] / (double)n;
    double var = sh2[0] / (double)n - mu * mu;
    float rs = (float)(1.0 / sqrt(var + 1e-5));
    float g = gamma[c] * rs;
    scale[c] = g;
    shift[c] = beta[c] - (float)mu * g;
  }
}

// ---------------- BN+relu, pack h1=yr+i*yi, symmetrize k=0/Nyquist ----------------
template<int B_, int H_, int Wf_>
__global__ void bn_pack(const float* __restrict__ Z, const float* __restrict__ scale,
                        const float* __restrict__ shift, float2* __restrict__ T) {
  __shared__ float sc[64], sf[64];
  const int t = threadIdx.x;
  if (t < 64) { sc[t] = scale[t]; sf[t] = shift[t]; }
  __syncthreads();
  const int i = blockIdx.x * 256 + t;  // B_*32*H_*Wf_
  const int k = i % Wf_;
  const int h = (i / Wf_) % H_;
  const int cc = (i / (Wf_ * H_)) % 32;
  const int b = i / (Wf_ * H_ * 32);
  const size_t chs = (size_t)B_ * H_ * Wf_;
  const size_t pix = ((size_t)b * H_ + h) * Wf_ + k;
  float r  = fmaxf(Z[cc * chs + pix] * sc[cc] + sf[cc], 0.f);
  float ii = fmaxf(Z[(cc + 32) * chs + pix] * sc[cc + 32] + sf[cc + 32], 0.f);
  if (k == 0 || k == Wf_ - 1) {
    const int hm = (H_ - h) & (H_ - 1);
    const size_t pixm = ((size_t)b * H_ + hm) * Wf_ + k;
    float r2 = fmaxf(Z[cc * chs + pixm] * sc[cc] + sf[cc], 0.f);
    float i2 = fmaxf(Z[(cc + 32) * chs + pixm] * sc[cc + 32] + sf[cc + 32], 0.f);
    r = 0.5f * (r + r2);
    ii = 0.5f * (ii - i2);
  }
  T[((size_t)(b * 32 + cc) * H_ + h) * Wf_ + k] = make_float2(r, ii);
}

// ---------------- epilogues ----------------
// out[:, 64:128] = w_local @ x_l + w_g2l @ x_g + b_local + b_g2l
__global__ void final_l(const float* __restrict__ x,
                        const float* __restrict__ w_local, const float* __restrict__ b_local,
                        const float* __restrict__ w_g2l, const float* __restrict__ b_g2l,
                        float* __restrict__ out) {
  __shared__ float wg[64 * 64], wl[64 * 64], bb[64];  // transposed wt[ci*64+o]
  const int t = threadIdx.x;
  for (int idx = t; idx < 4096; idx += 256) {
    wg[idx] = w_g2l[(idx & 63) * 64 + (idx >> 6)];
    wl[idx] = w_local[(idx & 63) * 64 + (idx >> 6)];
  }
  if (t < 64) bb[t] = b_local[t] + b_g2l[t];
  __syncthreads();
  const int p = blockIdx.x * 256 + t;
  const int hw = p & 65535;
  const int b = p >> 16;
  const float* xb = x + (size_t)b * 128 * 65536 + hw;
  float acc[64];
#pragma unroll
  for (int o = 0; o < 64; ++o) acc[o] = bb[o];
  for (int ci = 0; ci < 64; ++ci) {
    float xg = xb[(size_t)ci * 65536];
    float xl = xb[(size_t)(64 + ci) * 65536];
    const float4* g4 = (const float4*)&wg[ci * 64];
    const float4* l4 = (const float4*)&wl[ci * 64];
#pragma unroll
    for (int o4 = 0; o4 < 16; ++o4) {
      float4 a = g4[o4], c = l4[o4];
      acc[4 * o4 + 0] += a.x * xg + c.x * xl;
      acc[4 * o4 + 1] += a.y * xg + c.y * xl;
      acc[4 * o4 + 2] += a.z * xg + c.z * xl;
      acc[4 * o4 + 3] += a.w * xg + c.w * xl;
    }
  }
  float* ob = out + ((size_t)b * 128 + 64) * 65536 + hw;
#pragma unroll
  for (int o = 0; o < 64; ++o) ob[(size_t)o * 65536] = acc[o];
}

// out[:, 0:64] = w_out @ (y_g + tile(y2)) + w_l2g @ x_l + b_out + b_l2g
__global__ void final_g(const float* __restrict__ x,
                        const float* __restrict__ y_g, const float* __restrict__ y2,
                        const float* __restrict__ w_out, const float* __restrict__ b_out,
                        const float* __restrict__ w_l2g, const float* __restrict__ b_l2g,
                        float* __restrict__ out) {
  __shared__ float wo[32 * 64], wl[64 * 64], bb[64];  // transposed
  const int t = threadIdx.x;
  for (int idx = t; idx < 2048; idx += 256) wo[idx] = w_out[(idx & 63) * 32 + (idx >> 6)];
  for (int idx = t; idx < 4096; idx += 256) wl[idx] = w_l2g[(idx & 63) * 64 + (idx >> 6)];
  if (t < 64) bb[t] = b_out[t] + b_l2g[t];
  __syncthreads();
  const int p = blockIdx.x * 256 + t;
  const int hw = p & 65535;
  const int b = p >> 16;
  const int h = hw >> 8, w = hw & 255;
  const int hw2 = ((h & 127) << 7) + (w & 127);
  const float* xb = x + ((size_t)b * 128 + 64) * 65536 + hw;
  const float* gb = y_g + (size_t)b * 32 * 65536 + hw;
  const float* tb = y2 + (size_t)b * 32 * 16384 + hw2;
  float acc[64];
#pragma unroll
  for (int o = 0; o < 64; ++o) acc[o] = bb[o];
  for (int ci = 0; ci < 32; ++ci) {
    float s = gb[(size_t)ci * 65536] + tb[(size_t)ci * 16384];
    const float4* w4 = (const float4*)&wo[ci * 64];
#pragma unroll
    for (int o4 = 0; o4 < 16; ++o4) {
      float4 a = w4[o4];
      acc[4 * o4 + 0] += a.x * s;
      acc[4 * o4 + 1] += a.y * s;
      acc[4 * o4 + 2] += a.z * s;
      acc[4 * o4 + 3] += a.w * s;
    }
  }
  for (int ci = 0; ci < 64; ++ci) {
    float xl = xb[(size_t)ci * 65536];
    const float4* w4 = (const float4*)&wl[ci * 64];
#pragma unroll
    for (int o4 = 0; o4 < 16; ++o4) {
      float4 a = w4[o4];
      acc[4 * o4 + 0] += a.x * xl;
      acc[4 * o4 + 1] += a.y * xl;
      acc[4 * o4 + 2] += a.z * xl;
      acc[4 * o4 + 3] += a.w * xl;
    }
  }
  float* ob = out + (size_t)b * 128 * 65536 + hw;
#pragma unroll
  for (int o = 0; o < 64; ++o) ob[(size_t)o * 65536] = acc[o];
}

extern "C" void kernel_launch(void* const* d_in, const int* in_sizes, int n_in,
                              void* d_out, int out_size, void* d_ws, size_t ws_size,
                              hipStream_t stream) {
  (void)in_sizes; (void)n_in; (void)out_size; (void)ws_size;
  const float* x       = (const float*)d_in[0];
  const float* w_local = (const float*)d_in[1];
  const float* b_local = (const float*)d_in[2];
  const float* w_in    = (const float*)d_in[3];
  const float* b_in    = (const float*)d_in[4];
  const float* w_out   = (const float*)d_in[5];
  const float* b_out   = (const float*)d_in[6];
  const float* w_g2l   = (const float*)d_in[7];
  const float* b_g2l   = (const float*)d_in[8];
  const float* w_l2g   = (const float*)d_in[9];
  const float* b_l2g   = (const float*)d_in[10];
  const float* w_fu1   = (const float*)d_in[11];
  const float* b_fu1   = (const float*)d_in[12];
  const float* g_fu1   = (const float*)d_in[13];
  const float* be_fu1  = (const float*)d_in[14];
  const float* w_fu2   = (const float*)d_in[15];
  const float* b_fu2   = (const float*)d_in[16];
  const float* g_fu2   = (const float*)d_in[17];
  const float* be_fu2  = (const float*)d_in[18];
  float* out = (float*)d_out;

  // workspace layout (floats)
  float* ws   = (float*)d_ws;
  float* y_in = ws;                       // 4*32*256*256        = 8,388,608
  float* S1   = y_in + 8388608;           // 4*32*256*129 cplx   = 8,454,144 floats (also T1)
  float* Z1   = S1 + 8454144;             // 64*4*256*129        = 8,454,144 (y_g overlays after Z1 dead)
  float* y_g  = Z1;
  float* S2   = Z1 + 8454144;             // 4*32*128*65 cplx    = 2,129,920 floats (also T2)
  float* Z2   = S2 + 2129920;             // 64*4*128*65         = 2,129,920 (y2 overlays)
  float* y2   = Z2;
  float* st1  = Z2 + 2129920;             // scale[64], shift[64]
  float* st2  = st1 + 128;

  // y_in
  conv_in<<<1024, 256, 0, stream>>>(x, w_in, b_in, y_in);

  // ---- FU1 (256x256, Wf=129) ----
  rfft_rows<256, 8><<<32768, 128, 0, stream>>>(y_in, (float2*)S1);
  cfft_cols<256, 8><<<16512, 128, 0, stream>>>((float2*)S1, 129, -1.f);
  conv_spec<4, 256, 129><<<516, 256, 0, stream>>>((const float2*)S1, w_fu1, b_fu1, Z1);
  bn_stats<<<64, 256, 0, stream>>>(Z1, 132096, g_fu1, be_fu1, st1, st1 + 64);
  bn_pack<4, 256, 129><<<16512, 256, 0, stream>>>(Z1, st1, st1 + 64, (float2*)S1);
  cfft_cols<256, 8><<<16512, 128, 0, stream>>>((float2*)S1, 129, 1.f);
  irfft_rows<256, 8><<<32768, 128, 0, stream>>>((const float2*)S1, y_g, 1.f / 65536.f);

  // ---- FU2 / LFU (128x128, Wf=65) ----
  rfft_rows_lfu<<<16384, 64, 0, stream>>>(y_in, (float2*)S2);
  cfft_cols<128, 7><<<8320, 64, 0, stream>>>((float2*)S2, 65, -1.f);
  conv_spec<4, 128, 65><<<130, 256, 0, stream>>>((const float2*)S2, w_fu2, b_fu2, Z2);
  bn_stats<<<64, 256, 0, stream>>>(Z2, 33280, g_fu2, be_fu2, st2, st2 + 64);
  bn_pack<4, 128, 65><<<4160, 256, 0, stream>>>(Z2, st2, st2 + 64, (float2*)S2);
  cfft_cols<128, 7><<<8320, 64, 0, stream>>>((float2*)S2, 65, 1.f);
  irfft_rows<128, 7><<<16384, 64, 0, stream>>>((const float2*)S2, y2, 1.f / 16384.f);

  // ---- epilogues ----
  final_g<<<1024, 256, 0, stream>>>(x, y_g, y2, w_out, b_out, w_l2g, b_l2g, out);
  final_l<<<1024, 256, 0, stream>>>(x, w_local, b_local, w_g2l, b_g2l, out);
}

// Round 2
// 787.037 us; speedup vs baseline: 1.3840x; 1.3840x over previous
//
#include <hip/hip_runtime.h>
#include <math.h>

// FastFourierConvolution: B=4, C=128, H=W=256. Cg=Cl=64, Ci=32.
// FU1: (B,32,256,256) -> rfft2 -> conv64x64+BN+relu -> herm irfft2
// FU2 (LFU): y_in[:,24:32] quadrant-stacked to (B,32,128,128), same pipeline, tiled 2x2.

#define PI2 6.283185307179586f

// ---------------- FFT core: radix-2 DIT in LDS, blockDim == N/2 ----------------
template<int N, int LOG2N>
__device__ __forceinline__ void fft_stages(float* re, float* im, int tid, float sign) {
#pragma unroll
  for (int s = 1; s <= LOG2N; ++s) {
    __syncthreads();
    const int half = 1 << (s - 1);
    const int j = tid & (half - 1);
    const int i1 = ((tid >> (s - 1)) << s) + j;
    const int i2 = i1 + half;
    float ang = sign * (PI2 / (float)(1 << s)) * (float)j;
    float wr, wi;
    __sincosf(ang, &wi, &wr);
    float xr = re[i2], xi = im[i2];
    float vr = xr * wr - xi * wi;
    float vi = xr * wi + xi * wr;
    float ur = re[i1], ui = im[i1];
    re[i1] = ur + vr; im[i1] = ui + vi;
    re[i2] = ur - vr; im[i2] = ui - vi;
  }
  __syncthreads();
}

// row rfft: one block per row of length N (real) -> N/2+1 complex bins
template<int N, int LOG2N>
__global__ void rfft_rows(const float* __restrict__ src, float2* __restrict__ dst) {
  __shared__ float re[N], im[N];
  const int row = blockIdx.x;
  const int tid = threadIdx.x;  // N/2 threads
  const float* p = src + (size_t)row * N;
  for (int i = tid; i < N; i += N / 2) {
    int j = __brev((unsigned)i) >> (32 - LOG2N);
    re[j] = p[i];
    im[j] = 0.f;
  }
  fft_stages<N, LOG2N>(re, im, tid, -1.f);
  float2* q = dst + (size_t)row * (N / 2 + 1);
  for (int k = tid; k <= N / 2; k += N / 2) q[k] = make_float2(re[k], im[k]);
}

// LFU gather + row rfft (N=128): reads quadrants of y_in channels 24..31
__global__ void rfft_rows_lfu(const float* __restrict__ y_in, float2* __restrict__ dst) {
  __shared__ float re[128], im[128];
  const int bid = blockIdx.x;          // ((b*32+c2)*128 + h2)
  const int h2 = bid & 127;
  const int c2 = (bid >> 7) & 31;
  const int b  = bid >> 12;
  const int q = c2 >> 3, ch = c2 & 7;
  const int hs = ((q >> 1) << 7) + h2;
  const int ws0 = (q & 1) << 7;
  const float* p = y_in + (((size_t)(b * 32 + 24 + ch) * 256 + hs) * 256 + ws0);
  const int tid = threadIdx.x;  // 64
  for (int i = tid; i < 128; i += 64) {
    int j = __brev((unsigned)i) >> 25;
    re[j] = p[i];
    im[j] = 0.f;
  }
  fft_stages<128, 7>(re, im, tid, -1.f);
  float2* qp = dst + (size_t)bid * 65;
  for (int k = tid; k <= 64; k += 64) qp[k] = make_float2(re[k], im[k]);
}

// ---------------- tiled column FFT: block = TW columns x N rows, coalesced ----------------
// blockDim = 256. Thread t handles column c = t&15, rows/butterflies strided by 16.
template<int N, int LOG2N, int TW>
__global__ void cfft_cols_t(float2* __restrict__ data, int Wf, float sign, int tilesPerImg) {
  __shared__ float re[N][TW + 1], im[N][TW + 1];
  const int img = blockIdx.x / tilesPerImg;
  const int k0 = (blockIdx.x % tilesPerImg) * TW;
  const int cols = min(TW, Wf - k0);
  float2* base = data + (size_t)img * N * Wf + k0;
  const int t = threadIdx.x;
  const int c = t & (TW - 1);
  const int g = t >> 4;            // 0..15 (TW must be 16)
  const bool act = (c < cols);
  // load with bit-reversed row into LDS (coalesced: 16 consecutive lanes = 16 consecutive cols)
  for (int r = g; r < N; r += 16) {
    float2 v;
    if (act) v = base[(size_t)r * Wf + c];
    int j = __brev((unsigned)r) >> (32 - LOG2N);
    if (act) { re[j][c] = v.x; im[j][c] = v.y; }
  }
#pragma unroll
  for (int s = 1; s <= LOG2N; ++s) {
    __syncthreads();
    const int half = 1 << (s - 1);
    for (int bf = g; bf < N / 2; bf += 16) {
      if (!act) continue;
      const int j = bf & (half - 1);
      const int i1 = ((bf >> (s - 1)) << s) + j;
      const int i2 = i1 + half;
      float ang = sign * (PI2 / (float)(1 << s)) * (float)j;
      float wr, wi;
      __sincosf(ang, &wi, &wr);
      float xr = re[i2][c], xi = im[i2][c];
      float vr = xr * wr - xi * wi;
      float vi = xr * wi + xi * wr;
      float ur = re[i1][c], ui = im[i1][c];
      re[i1][c] = ur + vr; im[i1][c] = ui + vi;
      re[i2][c] = ur - vr; im[i2][c] = ui - vi;
    }
  }
  __syncthreads();
  for (int r = g; r < N; r += 16) {
    if (act) base[(size_t)r * Wf + c] = make_float2(re[r][c], im[r][c]);
  }
}

// row irfft: Hermitian-extend N/2+1 bins to N, inverse FFT, keep real*scale
template<int N, int LOG2N>
__global__ void irfft_rows(const float2* __restrict__ T, float* __restrict__ out, float scale) {
  __shared__ float re[N], im[N];
  const int row = blockIdx.x;
  const float2* p = T + (size_t)row * (N / 2 + 1);
  const int tid = threadIdx.x;  // N/2
  for (int i = tid; i < N; i += N / 2) {
    float2 v;
    if (i <= N / 2) v = p[i];
    else { v = p[N - i]; v.y = -v.y; }
    int j = __brev((unsigned)i) >> (32 - LOG2N);
    re[j] = v.x; im[j] = v.y;
  }
  fft_stages<N, LOG2N>(re, im, tid, 1.f);
  float* q = out + (size_t)row * N;
  for (int i = tid; i < N; i += N / 2) q[i] = re[i] * scale;
}

// ---------------- y_in = w_in(32x64) @ x[:, :64] + b_in ----------------
__global__ void conv_in(const float* __restrict__ x, const float* __restrict__ w,
                        const float* __restrict__ bias, float* __restrict__ y) {
  __shared__ float wt[32 * 64];  // transposed: wt[ci*32+o]
  __shared__ float bl[32];
  const int t = threadIdx.x;
  for (int idx = t; idx < 2048; idx += 256) wt[idx] = w[(idx & 31) * 64 + (idx >> 5)];
  if (t < 32) bl[t] = bias[t];
  __syncthreads();
  const int p = blockIdx.x * 256 + t;   // B*H*W = 262144
  const int hw = p & 65535;
  const int b = p >> 16;
  float acc[32];
#pragma unroll
  for (int o = 0; o < 32; ++o) acc[o] = bl[o];
  const float* xb = x + (size_t)b * 128 * 65536 + hw;
  for (int ci = 0; ci < 64; ++ci) {
    float v = xb[(size_t)ci * 65536];
    const float4* w4 = (const float4*)&wt[ci * 32];
#pragma unroll
    for (int o4 = 0; o4 < 8; ++o4) {
      float4 a = w4[o4];
      acc[4 * o4 + 0] += a.x * v;
      acc[4 * o4 + 1] += a.y * v;
      acc[4 * o4 + 2] += a.z * v;
      acc[4 * o4 + 3] += a.w * v;
    }
  }
  float* yb = y + (size_t)b * 32 * 65536 + hw;
#pragma unroll
  for (int o = 0; o < 32; ++o) yb[(size_t)o * 65536] = acc[o];
}

// ---------------- spectral conv: Z[co](b,h,k) = w(64x64) @ [Re;Im] + b ----------------
template<int B_, int H_, int Wf_>
__global__ void conv_spec(const float2* __restrict__ S, const float* __restrict__ w,
                          const float* __restrict__ bias, float* __restrict__ Z) {
  __shared__ float wt[64 * 64];  // transposed: wt[ci*64+co]
  __shared__ float bl[64];
  const int t = threadIdx.x;
  for (int idx = t; idx < 4096; idx += 256) wt[idx] = w[(idx & 63) * 64 + (idx >> 6)];
  if (t < 64) bl[t] = bias[t];
  __syncthreads();
  const int p = blockIdx.x * 256 + t;  // B_*H_*Wf_
  const int k = p % Wf_;
  const int h = (p / Wf_) % H_;
  const int b = p / (Wf_ * H_);
  float acc[64];
#pragma unroll
  for (int o = 0; o < 64; ++o) acc[o] = bl[o];
  for (int ci = 0; ci < 32; ++ci) {
    float2 s = S[((size_t)(b * 32 + ci) * H_ + h) * Wf_ + k];
    const float4* wr4 = (const float4*)&wt[ci * 64];
    const float4* wi4 = (const float4*)&wt[(ci + 32) * 64];
#pragma unroll
    for (int o4 = 0; o4 < 16; ++o4) {
      float4 a = wr4[o4], cc = wi4[o4];
      acc[4 * o4 + 0] += a.x * s.x + cc.x * s.y;
      acc[4 * o4 + 1] += a.y * s.x + cc.y * s.y;
      acc[4 * o4 + 2] += a.z * s.x + cc.z * s.y;
      acc[4 * o4 + 3] += a.w * s.x + cc.w * s.y;
    }
  }
  const size_t chs = (size_t)B_ * H_ * Wf_;
  const size_t pix = ((size_t)b * H_ + h) * Wf_ + k;
#pragma unroll
  for (int o = 0; o < 64; ++o) Z[o * chs + pix] = acc[o];
}

// ---------------- BN stats: stage 1 (64 channels x 32 slices), stage 2 finalize ----------------
__global__ void bn_stats_part(const float* __restrict__ Z, int chunk, double* __restrict__ pb) {
  const int c = blockIdx.x >> 5;
  const int sl = blockIdx.x & 31;
  const float* p = Z + (size_t)c * ((size_t)chunk * 32) + (size_t)sl * chunk;
  double s = 0.0, s2 = 0.0;
  for (int i = threadIdx.x; i < chunk; i += 256) {
    float v = p[i];
    s += v;
    s2 += (double)v * (double)v;
  }
  __shared__ double sh[256], sh2[256];
  sh[threadIdx.x] = s; sh2[threadIdx.x] = s2;
  __syncthreads();
  for (int off = 128; off > 0; off >>= 1) {
    if (threadIdx.x < off) { sh[threadIdx.x] += sh[threadIdx.x + off]; sh2[threadIdx.x] += sh2[threadIdx.x + off]; }
    __syncthreads();
  }
  if (threadIdx.x == 0) { pb[2 * blockIdx.x] = sh[0]; pb[2 * blockIdx.x + 1] = sh2[0]; }
}

__global__ void bn_finalize(const double* __restrict__ pb, int n,
                            const float* __restrict__ gamma, const float* __restrict__ beta,
                            float* __restrict__ scale, float* __restrict__ shift) {
  const int c = threadIdx.x;  // 64 threads
  double s = 0.0, s2 = 0.0;
  for (int i = 0; i < 32; ++i) { s += pb[2 * (c * 32 + i)]; s2 += pb[2 * (c * 32 + i) + 1]; }
  double mu = s / (double)n;
  double var = s2 / (double)n - mu * mu;
  float rs = (float)(1.0 / sqrt(var + 1e-5));
  float g = gamma[c] * rs;
  scale[c] = g;
  shift[c] = beta[c] - (float)mu * g;
}

// ---------------- BN+relu, pack h1=yr+i*yi, symmetrize k=0/Nyquist ----------------
template<int B_, int H_, int Wf_>
__global__ void bn_pack(const float* __restrict__ Z, const float* __restrict__ scale,
                        const float* __restrict__ shift, float2* __restrict__ T) {
  __shared__ float sc[64], sf[64];
  const int t = threadIdx.x;
  if (t < 64) { sc[t] = scale[t]; sf[t] = shift[t]; }
  __syncthreads();
  const int i = blockIdx.x * 256 + t;  // B_*32*H_*Wf_
  const int k = i % Wf_;
  const int h = (i / Wf_) % H_;
  const int cc = (i / (Wf_ * H_)) % 32;
  const int b = i / (Wf_ * H_ * 32);
  const size_t chs = (size_t)B_ * H_ * Wf_;
  const size_t pix = ((size_t)b * H_ + h) * Wf_ + k;
  float r  = fmaxf(Z[cc * chs + pix] * sc[cc] + sf[cc], 0.f);
  float ii = fmaxf(Z[(cc + 32) * chs + pix] * sc[cc + 32] + sf[cc + 32], 0.f);
  if (k == 0 || k == Wf_ - 1) {
    const int hm = (H_ - h) & (H_ - 1);
    const size_t pixm = ((size_t)b * H_ + hm) * Wf_ + k;
    float r2 = fmaxf(Z[cc * chs + pixm] * sc[cc] + sf[cc], 0.f);
    float i2 = fmaxf(Z[(cc + 32) * chs + pixm] * sc[cc + 32] + sf[cc + 32], 0.f);
    r = 0.5f * (r + r2);
    ii = 0.5f * (ii - i2);
  }
  T[((size_t)(b * 32 + cc) * H_ + h) * Wf_ + k] = make_float2(r, ii);
}

// ---------------- epilogues ----------------
__global__ void final_l(const float* __restrict__ x,
                        const float* __restrict__ w_local, const float* __restrict__ b_local,
                        const float* __restrict__ w_g2l, const float* __restrict__ b_g2l,
                        float* __restrict__ out) {
  __shared__ float wg[64 * 64], wl[64 * 64], bb[64];  // transposed wt[ci*64+o]
  const int t = threadIdx.x;
  for (int idx = t; idx < 4096; idx += 256) {
    wg[idx] = w_g2l[(idx & 63) * 64 + (idx >> 6)];
    wl[idx] = w_local[(idx & 63) * 64 + (idx >> 6)];
  }
  if (t < 64) bb[t] = b_local[t] + b_g2l[t];
  __syncthreads();
  const int p = blockIdx.x * 256 + t;
  const int hw = p & 65535;
  const int b = p >> 16;
  const float* xb = x + (size_t)b * 128 * 65536 + hw;
  float acc[64];
#pragma unroll
  for (int o = 0; o < 64; ++o) acc[o] = bb[o];
  for (int ci = 0; ci < 64; ++ci) {
    float xg = xb[(size_t)ci * 65536];
    float xl = xb[(size_t)(64 + ci) * 65536];
    const float4* g4 = (const float4*)&wg[ci * 64];
    const float4* l4 = (const float4*)&wl[ci * 64];
#pragma unroll
    for (int o4 = 0; o4 < 16; ++o4) {
      float4 a = g4[o4], cc = l4[o4];
      acc[4 * o4 + 0] += a.x * xg + cc.x * xl;
      acc[4 * o4 + 1] += a.y * xg + cc.y * xl;
      acc[4 * o4 + 2] += a.z * xg + cc.z * xl;
      acc[4 * o4 + 3] += a.w * xg + cc.w * xl;
    }
  }
  float* ob = out + ((size_t)b * 128 + 64) * 65536 + hw;
#pragma unroll
  for (int o = 0; o < 64; ++o) ob[(size_t)o * 65536] = acc[o];
}

__global__ void final_g(const float* __restrict__ x,
                        const float* __restrict__ y_g, const float* __restrict__ y2,
                        const float* __restrict__ w_out, const float* __restrict__ b_out,
                        const float* __restrict__ w_l2g, const float* __restrict__ b_l2g,
                        float* __restrict__ out) {
  __shared__ float wo[32 * 64], wl[64 * 64], bb[64];  // transposed
  const int t = threadIdx.x;
  for (int idx = t; idx < 2048; idx += 256) wo[idx] = w_out[(idx & 63) * 32 + (idx >> 6)];
  for (int idx = t; idx < 4096; idx += 256) wl[idx] = w_l2g[(idx & 63) * 64 + (idx >> 6)];
  if (t < 64) bb[t] = b_out[t] + b_l2g[t];
  __syncthreads();
  const int p = blockIdx.x * 256 + t;
  const int hw = p & 65535;
  const int b = p >> 16;
  const int h = hw >> 8, w = hw & 255;
  const int hw2 = ((h & 127) << 7) + (w & 127);
  const float* xb = x + ((size_t)b * 128 + 64) * 65536 + hw;
  const float* gb = y_g + (size_t)b * 32 * 65536 + hw;
  const float* tb = y2 + (size_t)b * 32 * 16384 + hw2;
  float acc[64];
#pragma unroll
  for (int o = 0; o < 64; ++o) acc[o] = bb[o];
  for (int ci = 0; ci < 32; ++ci) {
    float s = gb[(size_t)ci * 65536] + tb[(size_t)ci * 16384];
    const float4* w4 = (const float4*)&wo[ci * 64];
#pragma unroll
    for (int o4 = 0; o4 < 16; ++o4) {
      float4 a = w4[o4];
      acc[4 * o4 + 0] += a.x * s;
      acc[4 * o4 + 1] += a.y * s;
      acc[4 * o4 + 2] += a.z * s;
      acc[4 * o4 + 3] += a.w * s;
    }
  }
  for (int ci = 0; ci < 64; ++ci) {
    float xl = xb[(size_t)ci * 65536];
    const float4* w4 = (const float4*)&wl[ci * 64];
#pragma unroll
    for (int o4 = 0; o4 < 16; ++o4) {
      float4 a = w4[o4];
      acc[4 * o4 + 0] += a.x * xl;
      acc[4 * o4 + 1] += a.y * xl;
      acc[4 * o4 + 2] += a.z * xl;
      acc[4 * o4 + 3] += a.w * xl;
    }
  }
  float* ob = out + (size_t)b * 128 * 65536 + hw;
#pragma unroll
  for (int o = 0; o < 64; ++o) ob[(size_t)o * 65536] = acc[o];
}

extern "C" void kernel_launch(void* const* d_in, const int* in_sizes, int n_in,
                              void* d_out, int out_size, void* d_ws, size_t ws_size,
                              hipStream_t stream) {
  (void)in_sizes; (void)n_in; (void)out_size; (void)ws_size;
  const float* x       = (const float*)d_in[0];
  const float* w_local = (const float*)d_in[1];
  const float* b_local = (const float*)d_in[2];
  const float* w_in    = (const float*)d_in[3];
  const float* b_in    = (const float*)d_in[4];
  const float* w_out   = (const float*)d_in[5];
  const float* b_out   = (const float*)d_in[6];
  const float* w_g2l   = (const float*)d_in[7];
  const float* b_g2l   = (const float*)d_in[8];
  const float* w_l2g   = (const float*)d_in[9];
  const float* b_l2g   = (const float*)d_in[10];
  const float* w_fu1   = (const float*)d_in[11];
  const float* b_fu1   = (const float*)d_in[12];
  const float* g_fu1   = (const float*)d_in[13];
  const float* be_fu1  = (const float*)d_in[14];
  const float* w_fu2   = (const float*)d_in[15];
  const float* b_fu2   = (const float*)d_in[16];
  const float* g_fu2   = (const float*)d_in[17];
  const float* be_fu2  = (const float*)d_in[18];
  float* out = (float*)d_out;

  // workspace layout (floats)
  float* ws   = (float*)d_ws;
  float* y_in = ws;                       // 8,388,608
  float* S1   = y_in + 8388608;           // 8,454,144 floats (spectral FU1; dead during bn_stats1)
  float* Z1   = S1 + 8454144;             // 8,454,144 (y_g overlays after Z1 dead)
  float* y_g  = Z1;
  float* S2   = Z1 + 8454144;             // 2,129,920 floats (spectral FU2; dead during bn_stats2)
  float* Z2   = S2 + 2129920;             // 2,129,920 (y2 overlays)
  float* y2   = Z2;
  float* st1  = Z2 + 2129920;             // scale[64], shift[64]
  float* st2  = st1 + 128;
  double* pb1 = (double*)S1;              // 64*32*2 doubles, overlaid on dead S1
  double* pb2 = (double*)S2;              // overlaid on dead S2

  // y_in
  conv_in<<<1024, 256, 0, stream>>>(x, w_in, b_in, y_in);

  // ---- FU1 (256x256, Wf=129) ----
  rfft_rows<256, 8><<<32768, 128, 0, stream>>>(y_in, (float2*)S1);
  cfft_cols_t<256, 8, 16><<<128 * 9, 256, 0, stream>>>((float2*)S1, 129, -1.f, 9);
  conv_spec<4, 256, 129><<<516, 256, 0, stream>>>((const float2*)S1, w_fu1, b_fu1, Z1);
  bn_stats_part<<<2048, 256, 0, stream>>>(Z1, 4128, pb1);
  bn_finalize<<<1, 64, 0, stream>>>(pb1, 132096, g_fu1, be_fu1, st1, st1 + 64);
  bn_pack<4, 256, 129><<<16512, 256, 0, stream>>>(Z1, st1, st1 + 64, (float2*)S1);
  cfft_cols_t<256, 8, 16><<<128 * 9, 256, 0, stream>>>((float2*)S1, 129, 1.f, 9);
  irfft_rows<256, 8><<<32768, 128, 0, stream>>>((const float2*)S1, y_g, 1.f / 65536.f);

  // ---- FU2 / LFU (128x128, Wf=65) ----
  rfft_rows_lfu<<<16384, 64, 0, stream>>>(y_in, (float2*)S2);
  cfft_cols_t<128, 7, 16><<<128 * 5, 256, 0, stream>>>((float2*)S2, 65, -1.f, 5);
  conv_spec<4, 128, 65><<<130, 256, 0, stream>>>((const float2*)S2, w_fu2, b_fu2, Z2);
  bn_stats_part<<<2048, 256, 0, stream>>>(Z2, 1040, pb2);
  bn_finalize<<<1, 64, 0, stream>>>(pb2, 33280, g_fu2, be_fu2, st2, st2 + 64);
  bn_pack<4, 128, 65><<<4160, 256, 0, stream>>>(Z2, st2, st2 + 64, (float2*)S2);
  cfft_cols_t<128, 7, 16><<<128 * 5, 256, 0, stream>>>((float2*)S2, 65, 1.f, 5);
  irfft_rows<128, 7><<<16384, 64, 0, stream>>>((const float2*)S2, y2, 1.f / 16384.f);

  // ---- epilogues ----
  final_g<<<1024, 256, 0, stream>>>(x, y_g, y2, w_out, b_out, w_l2g, b_l2g, out);
  final_l<<<1024, 256, 0, stream>>>(x, w_local, b_local, w_g2l, b_g2l, out);
}

// Round 3
// 786.293 us; speedup vs baseline: 1.3853x; 1.0009x over previous
//
#include <hip/hip_runtime.h>
#include <math.h>

// FastFourierConvolution: B=4, C=128, H=W=256. Cg=Cl=64, Ci=32.
// FU1: (B,32,256,256) -> rfft2 -> conv64x64+BN+relu -> herm irfft2
// FU2 (LFU): y_in[:,24:32] quadrant-stacked to (B,32,128,128), same pipeline, tiled 2x2.

#define PI2 6.283185307179586f

__device__ __forceinline__ void fma4(float4& a, float w, const float4& v) {
  a.x += w * v.x; a.y += w * v.y; a.z += w * v.z; a.w += w * v.w;
}
__device__ __forceinline__ float4 add4(const float4& a, const float4& b) {
  return make_float4(a.x + b.x, a.y + b.y, a.z + b.z, a.w + b.w);
}

// ---------------- FFT core: radix-2 DIT in LDS, blockDim == N/2 ----------------
template<int N, int LOG2N>
__device__ __forceinline__ void fft_stages(float* re, float* im, int tid, float sign) {
#pragma unroll
  for (int s = 1; s <= LOG2N; ++s) {
    __syncthreads();
    const int half = 1 << (s - 1);
    const int j = tid & (half - 1);
    const int i1 = ((tid >> (s - 1)) << s) + j;
    const int i2 = i1 + half;
    float ang = sign * (PI2 / (float)(1 << s)) * (float)j;
    float wr, wi;
    __sincosf(ang, &wi, &wr);
    float xr = re[i2], xi = im[i2];
    float vr = xr * wr - xi * wi;
    float vi = xr * wi + xi * wr;
    float ur = re[i1], ui = im[i1];
    re[i1] = ur + vr; im[i1] = ui + vi;
    re[i2] = ur - vr; im[i2] = ui - vi;
  }
  __syncthreads();
}

// row rfft: one block per row of length N (real) -> N/2+1 complex bins
template<int N, int LOG2N>
__global__ void rfft_rows(const float* __restrict__ src, float2* __restrict__ dst) {
  __shared__ float re[N], im[N];
  const int row = blockIdx.x;
  const int tid = threadIdx.x;  // N/2 threads
  const float* p = src + (size_t)row * N;
  for (int i = tid; i < N; i += N / 2) {
    int j = __brev((unsigned)i) >> (32 - LOG2N);
    re[j] = p[i];
    im[j] = 0.f;
  }
  fft_stages<N, LOG2N>(re, im, tid, -1.f);
  float2* q = dst + (size_t)row * (N / 2 + 1);
  for (int k = tid; k <= N / 2; k += N / 2) q[k] = make_float2(re[k], im[k]);
}

// LFU gather + row rfft (N=128): reads quadrants of y_in channels 24..31
__global__ void rfft_rows_lfu(const float* __restrict__ y_in, float2* __restrict__ dst) {
  __shared__ float re[128], im[128];
  const int bid = blockIdx.x;          // ((b*32+c2)*128 + h2)
  const int h2 = bid & 127;
  const int c2 = (bid >> 7) & 31;
  const int b  = bid >> 12;
  const int q = c2 >> 3, ch = c2 & 7;
  const int hs = ((q >> 1) << 7) + h2;
  const int ws0 = (q & 1) << 7;
  const float* p = y_in + (((size_t)(b * 32 + 24 + ch) * 256 + hs) * 256 + ws0);
  const int tid = threadIdx.x;  // 64
  for (int i = tid; i < 128; i += 64) {
    int j = __brev((unsigned)i) >> 25;
    re[j] = p[i];
    im[j] = 0.f;
  }
  fft_stages<128, 7>(re, im, tid, -1.f);
  float2* qp = dst + (size_t)bid * 65;
  for (int k = tid; k <= 64; k += 64) qp[k] = make_float2(re[k], im[k]);
}

// ---------------- tiled forward column FFT: block = 16 columns x N rows ----------------
template<int N, int LOG2N, int TW>
__global__ void cfft_cols_t(float2* __restrict__ data, int Wf, float sign, int tilesPerImg) {
  __shared__ float re[N][TW + 1], im[N][TW + 1];
  const int img = blockIdx.x / tilesPerImg;
  const int k0 = (blockIdx.x % tilesPerImg) * TW;
  const int cols = min(TW, Wf - k0);
  float2* base = data + (size_t)img * N * Wf + k0;
  const int t = threadIdx.x;
  const int c = t & (TW - 1);
  const int g = t >> 4;
  const bool act = (c < cols);
  for (int r = g; r < N; r += 16) {
    float2 v;
    if (act) v = base[(size_t)r * Wf + c];
    int j = __brev((unsigned)r) >> (32 - LOG2N);
    if (act) { re[j][c] = v.x; im[j][c] = v.y; }
  }
#pragma unroll
  for (int s = 1; s <= LOG2N; ++s) {
    __syncthreads();
    const int half = 1 << (s - 1);
    for (int bf = g; bf < N / 2; bf += 16) {
      if (!act) continue;
      const int j = bf & (half - 1);
      const int i1 = ((bf >> (s - 1)) << s) + j;
      const int i2 = i1 + half;
      float ang = sign * (PI2 / (float)(1 << s)) * (float)j;
      float wr, wi;
      __sincosf(ang, &wi, &wr);
      float xr = re[i2][c], xi = im[i2][c];
      float vr = xr * wr - xi * wi;
      float vi = xr * wi + xi * wr;
      float ur = re[i1][c], ui = im[i1][c];
      re[i1][c] = ur + vr; im[i1][c] = ui + vi;
      re[i2][c] = ur - vr; im[i2][c] = ui - vi;
    }
  }
  __syncthreads();
  for (int r = g; r < N; r += 16) {
    if (act) base[(size_t)r * Wf + c] = make_float2(re[r][c], im[r][c]);
  }
}

// ---------------- fused BN+relu+symmetrize + inverse column FFT ----------------
// reads Z (channel-major), applies scale/shift/relu, symmetrizes k=0/Nyquist, writes T columns
template<int N, int LOG2N, int TW>
__global__ void cfft_inv_bn(const float* __restrict__ Z, const float* __restrict__ scale,
                            const float* __restrict__ shift, float2* __restrict__ T,
                            int Wf, int tilesPerImg, int chs) {
  __shared__ float re[N][TW + 1], im[N][TW + 1];
  const int img = blockIdx.x / tilesPerImg;    // b*32 + cc
  const int b = img >> 5, cc = img & 31;
  const int k0 = (blockIdx.x % tilesPerImg) * TW;
  const int cols = min(TW, Wf - k0);
  const int t = threadIdx.x;
  const int c = t & (TW - 1);
  const int g = t >> 4;
  const bool act = (c < cols);
  const int kk = k0 + c;
  const float scr = scale[cc], sfr = shift[cc];
  const float sci = scale[cc + 32], sfi = shift[cc + 32];
  const float* Zr = Z + (size_t)cc * chs + (size_t)b * N * Wf;
  const float* Zi = Z + (size_t)(cc + 32) * chs + (size_t)b * N * Wf;
  const bool edge = (kk == 0 || kk == Wf - 1);
  for (int r = g; r < N; r += 16) {
    float vr = 0.f, vi = 0.f;
    if (act) {
      size_t p = (size_t)r * Wf + kk;
      float yr = fmaxf(Zr[p] * scr + sfr, 0.f);
      float yi = fmaxf(Zi[p] * sci + sfi, 0.f);
      if (edge) {
        int rm = (N - r) & (N - 1);
        size_t pm = (size_t)rm * Wf + kk;
        float yr2 = fmaxf(Zr[pm] * scr + sfr, 0.f);
        float yi2 = fmaxf(Zi[pm] * sci + sfi, 0.f);
        yr = 0.5f * (yr + yr2);
        yi = 0.5f * (yi - yi2);
      }
      vr = yr; vi = yi;
    }
    int j = __brev((unsigned)r) >> (32 - LOG2N);
    if (act) { re[j][c] = vr; im[j][c] = vi; }
  }
#pragma unroll
  for (int s = 1; s <= LOG2N; ++s) {
    __syncthreads();
    const int half = 1 << (s - 1);
    for (int bf = g; bf < N / 2; bf += 16) {
      if (!act) continue;
      const int jq = bf & (half - 1);
      const int i1 = ((bf >> (s - 1)) << s) + jq;
      const int i2 = i1 + half;
      float ang = (PI2 / (float)(1 << s)) * (float)jq;
      float wr, wi;
      __sincosf(ang, &wi, &wr);
      float xr = re[i2][c], xi = im[i2][c];
      float pr = xr * wr - xi * wi;
      float pi = xr * wi + xi * wr;
      float ur = re[i1][c], ui = im[i1][c];
      re[i1][c] = ur + pr; im[i1][c] = ui + pi;
      re[i2][c] = ur - pr; im[i2][c] = ui - pi;
    }
  }
  __syncthreads();
  float2* base = T + (size_t)img * N * Wf + k0;
  for (int r = g; r < N; r += 16)
    if (act) base[(size_t)r * Wf + c] = make_float2(re[r][c], im[r][c]);
}

// row irfft: Hermitian-extend N/2+1 bins to N, inverse FFT, keep real*scale
template<int N, int LOG2N>
__global__ void irfft_rows(const float2* __restrict__ T, float* __restrict__ out, float scale) {
  __shared__ float re[N], im[N];
  const int row = blockIdx.x;
  const float2* p = T + (size_t)row * (N / 2 + 1);
  const int tid = threadIdx.x;  // N/2
  for (int i = tid; i < N; i += N / 2) {
    float2 v;
    if (i <= N / 2) v = p[i];
    else { v = p[N - i]; v.y = -v.y; }
    int j = __brev((unsigned)i) >> (32 - LOG2N);
    re[j] = v.x; im[j] = v.y;
  }
  fft_stages<N, LOG2N>(re, im, tid, 1.f);
  float* q = out + (size_t)row * N;
  for (int i = tid; i < N; i += N / 2) q[i] = re[i] * scale;
}

// ---------------- y_in = w_in(32x64) @ x[:, :64] + b_in (float4 pixels) ----------------
__global__ void conv_in_v(const float* __restrict__ x, const float* __restrict__ w,
                          const float* __restrict__ bias, float* __restrict__ y) {
  __shared__ float wt[32 * 64];  // wt[ci*32+o]
  __shared__ float bl[32];
  const int t = threadIdx.x;
  for (int idx = t; idx < 2048; idx += 256) wt[idx] = w[(idx & 31) * 64 + (idx >> 5)];
  if (t < 32) bl[t] = bias[t];
  __syncthreads();
  const int og = t >> 6;                       // 0..3 -> outputs og*8..og*8+7 (wave-uniform)
  const int p4 = blockIdx.x * 64 + (t & 63);   // 65536 float4-pixels
  const int hw4 = p4 & 16383;
  const int b = p4 >> 14;
  const float4* xb = (const float4*)x + (size_t)b * 128 * 16384 + hw4;
  float4 acc[8];
#pragma unroll
  for (int o = 0; o < 8; ++o) { float bv = bl[og * 8 + o]; acc[o] = make_float4(bv, bv, bv, bv); }
  for (int ci = 0; ci < 64; ++ci) {
    float4 v = xb[(size_t)ci * 16384];
    const float4* w4p = (const float4*)&wt[ci * 32 + og * 8];
    float4 a = w4p[0], c = w4p[1];
    fma4(acc[0], a.x, v); fma4(acc[1], a.y, v); fma4(acc[2], a.z, v); fma4(acc[3], a.w, v);
    fma4(acc[4], c.x, v); fma4(acc[5], c.y, v); fma4(acc[6], c.z, v); fma4(acc[7], c.w, v);
  }
  float4* yb = (float4*)y + (size_t)(b * 32 + og * 8) * 16384 + hw4;
#pragma unroll
  for (int o = 0; o < 8; ++o) yb[(size_t)o * 16384] = acc[o];
}

// ---------------- spectral conv: pairs of complex pixels (float4 loads) ----------------
template<int B_, int H_, int Wf_>
__global__ void conv_spec_v(const float4* __restrict__ S4, const float* __restrict__ w,
                            const float* __restrict__ bias, float2* __restrict__ Z2) {
  constexpr int PP = H_ * Wf_ / 2;      // complex pairs per (b,ci) plane
  constexpr int CHS2 = B_ * PP;         // pairs per out-channel
  __shared__ float wt[64 * 64];         // wt[ci*64+co]
  __shared__ float bl[64];
  const int t = threadIdx.x;
  for (int idx = t; idx < 4096; idx += 256) wt[idx] = w[(idx & 63) * 64 + (idx >> 6)];
  if (t < 64) bl[t] = bias[t];
  __syncthreads();
  const int og = t >> 7;                        // 0/1 -> 32 outputs (wave-uniform)
  const int j2 = blockIdx.x * 128 + (t & 127);  // global pair index
  const int b = j2 / PP;
  const int jp = j2 - b * PP;
  float2 acc[32];
#pragma unroll
  for (int o = 0; o < 32; ++o) { float bv = bl[og * 32 + o]; acc[o] = make_float2(bv, bv); }
  const float4* sp = S4 + (size_t)(b * 32) * PP + jp;
  for (int ci = 0; ci < 32; ++ci) {
    float4 sv = sp[(size_t)ci * PP];   // two complex: (x,y) (z,w)
    const float4* wr4 = (const float4*)&wt[ci * 64 + og * 32];
    const float4* wi4 = (const float4*)&wt[(ci + 32) * 64 + og * 32];
#pragma unroll
    for (int o4 = 0; o4 < 8; ++o4) {
      float4 a = wr4[o4], c = wi4[o4];
      acc[4 * o4 + 0].x += a.x * sv.x + c.x * sv.y;  acc[4 * o4 + 0].y += a.x * sv.z + c.x * sv.w;
      acc[4 * o4 + 1].x += a.y * sv.x + c.y * sv.y;  acc[4 * o4 + 1].y += a.y * sv.z + c.y * sv.w;
      acc[4 * o4 + 2].x += a.z * sv.x + c.z * sv.y;  acc[4 * o4 + 2].y += a.z * sv.z + c.z * sv.w;
      acc[4 * o4 + 3].x += a.w * sv.x + c.w * sv.y;  acc[4 * o4 + 3].y += a.w * sv.z + c.w * sv.w;
    }
  }
#pragma unroll
  for (int o = 0; o < 32; ++o) Z2[(size_t)(og * 32 + o) * CHS2 + j2] = acc[o];
}

// ---------------- BN stats: stage 1 (64 channels x 32 slices), stage 2 finalize ----------------
__global__ void bn_stats_part(const float* __restrict__ Z, int chunk, double* __restrict__ pb) {
  const int c = blockIdx.x >> 5;
  const int sl = blockIdx.x & 31;
  const float* p = Z + (size_t)c * ((size_t)chunk * 32) + (size_t)sl * chunk;
  double s = 0.0, s2 = 0.0;
  for (int i = threadIdx.x; i < chunk; i += 256) {
    float v = p[i];
    s += v;
    s2 += (double)v * (double)v;
  }
  __shared__ double sh[256], sh2[256];
  sh[threadIdx.x] = s; sh2[threadIdx.x] = s2;
  __syncthreads();
  for (int off = 128; off > 0; off >>= 1) {
    if (threadIdx.x < off) { sh[threadIdx.x] += sh[threadIdx.x + off]; sh2[threadIdx.x] += sh2[threadIdx.x + off]; }
    __syncthreads();
  }
  if (threadIdx.x == 0) { pb[2 * blockIdx.x] = sh[0]; pb[2 * blockIdx.x + 1] = sh2[0]; }
}

__global__ void bn_finalize(const double* __restrict__ pb, int n,
                            const float* __restrict__ gamma, const float* __restrict__ beta,
                            float* __restrict__ scale, float* __restrict__ shift) {
  const int c = threadIdx.x;  // 64 threads
  double s = 0.0, s2 = 0.0;
  for (int i = 0; i < 32; ++i) { s += pb[2 * (c * 32 + i)]; s2 += pb[2 * (c * 32 + i) + 1]; }
  double mu = s / (double)n;
  double var = s2 / (double)n - mu * mu;
  float rs = (float)(1.0 / sqrt(var + 1e-5));
  float g = gamma[c] * rs;
  scale[c] = g;
  shift[c] = beta[c] - (float)mu * g;
}

// ---------------- epilogues (float4 pixels, outputs split across wave-uniform groups) ------------
__global__ void final_l_v(const float* __restrict__ x,
                          const float* __restrict__ w_local, const float* __restrict__ b_local,
                          const float* __restrict__ w_g2l, const float* __restrict__ b_g2l,
                          float* __restrict__ out) {
  __shared__ float wg[64 * 64], wl[64 * 64], bb[64];
  const int t = threadIdx.x;
  for (int idx = t; idx < 4096; idx += 256) {
    wg[idx] = w_g2l[(idx & 63) * 64 + (idx >> 6)];
    wl[idx] = w_local[(idx & 63) * 64 + (idx >> 6)];
  }
  if (t < 64) bb[t] = b_local[t] + b_g2l[t];
  __syncthreads();
  const int og = t >> 6;                       // 16 outputs
  const int p4 = blockIdx.x * 64 + (t & 63);
  const int hw4 = p4 & 16383;
  const int b = p4 >> 14;
  const float4* xb = (const float4*)x + (size_t)b * 128 * 16384 + hw4;
  float4 acc[16];
#pragma unroll
  for (int o = 0; o < 16; ++o) { float bv = bb[og * 16 + o]; acc[o] = make_float4(bv, bv, bv, bv); }
  for (int ci = 0; ci < 64; ++ci) {
    float4 xg = xb[(size_t)ci * 16384];
    float4 xl = xb[(size_t)(64 + ci) * 16384];
    const float4* g4 = (const float4*)&wg[ci * 64 + og * 16];
    const float4* l4 = (const float4*)&wl[ci * 64 + og * 16];
#pragma unroll
    for (int o4 = 0; o4 < 4; ++o4) {
      float4 a = g4[o4], cw = l4[o4];
      fma4(acc[4 * o4 + 0], a.x, xg); fma4(acc[4 * o4 + 0], cw.x, xl);
      fma4(acc[4 * o4 + 1], a.y, xg); fma4(acc[4 * o4 + 1], cw.y, xl);
      fma4(acc[4 * o4 + 2], a.z, xg); fma4(acc[4 * o4 + 2], cw.z, xl);
      fma4(acc[4 * o4 + 3], a.w, xg); fma4(acc[4 * o4 + 3], cw.w, xl);
    }
  }
  float4* ob = (float4*)out + (size_t)(b * 128 + 64 + og * 16) * 16384 + hw4;
#pragma unroll
  for (int o = 0; o < 16; ++o) ob[(size_t)o * 16384] = acc[o];
}

__global__ void final_g_v(const float* __restrict__ x,
                          const float* __restrict__ y_g, const float* __restrict__ y2,
                          const float* __restrict__ w_out, const float* __restrict__ b_out,
                          const float* __restrict__ w_l2g, const float* __restrict__ b_l2g,
                          float* __restrict__ out) {
  __shared__ float wo[32 * 64], wl[64 * 64], bb[64];
  const int t = threadIdx.x;
  for (int idx = t; idx < 2048; idx += 256) wo[idx] = w_out[(idx & 63) * 32 + (idx >> 6)];
  for (int idx = t; idx < 4096; idx += 256) wl[idx] = w_l2g[(idx & 63) * 64 + (idx >> 6)];
  if (t < 64) bb[t] = b_out[t] + b_l2g[t];
  __syncthreads();
  const int og = t >> 6;                       // 16 outputs
  const int p4 = blockIdx.x * 64 + (t & 63);
  const int hw4 = p4 & 16383;
  const int b = p4 >> 14;
  const int h = hw4 >> 6;                      // 64 float4 per row
  const int w4 = hw4 & 63;
  const int hw2_4 = ((h & 127) << 5) + (w4 & 31);
  const float4* xb = (const float4*)x + (size_t)(b * 128 + 64) * 16384 + hw4;
  const float4* gb = (const float4*)y_g + (size_t)b * 32 * 16384 + hw4;
  const float4* tb = (const float4*)y2 + (size_t)b * 32 * 4096 + hw2_4;
  float4 acc[16];
#pragma unroll
  for (int o = 0; o < 16; ++o) { float bv = bb[og * 16 + o]; acc[o] = make_float4(bv, bv, bv, bv); }
  for (int ci = 0; ci < 32; ++ci) {
    float4 s = add4(gb[(size_t)ci * 16384], tb[(size_t)ci * 4096]);
    const float4* w4p = (const float4*)&wo[ci * 64 + og * 16];
#pragma unroll
    for (int o4 = 0; o4 < 4; ++o4) {
      float4 a = w4p[o4];
      fma4(acc[4 * o4 + 0], a.x, s);
      fma4(acc[4 * o4 + 1], a.y, s);
      fma4(acc[4 * o4 + 2], a.z, s);
      fma4(acc[4 * o4 + 3], a.w, s);
    }
  }
  for (int ci = 0; ci < 64; ++ci) {
    float4 xl = xb[(size_t)ci * 16384];
    const float4* w4p = (const float4*)&wl[ci * 64 + og * 16];
#pragma unroll
    for (int o4 = 0; o4 < 4; ++o4) {
      float4 a = w4p[o4];
      fma4(acc[4 * o4 + 0], a.x, xl);
      fma4(acc[4 * o4 + 1], a.y, xl);
      fma4(acc[4 * o4 + 2], a.z, xl);
      fma4(acc[4 * o4 + 3], a.w, xl);
    }
  }
  float4* ob = (float4*)out + (size_t)(b * 128 + og * 16) * 16384 + hw4;
#pragma unroll
  for (int o = 0; o < 16; ++o) ob[(size_t)o * 16384] = acc[o];
}

extern "C" void kernel_launch(void* const* d_in, const int* in_sizes, int n_in,
                              void* d_out, int out_size, void* d_ws, size_t ws_size,
                              hipStream_t stream) {
  (void)in_sizes; (void)n_in; (void)out_size; (void)ws_size;
  const float* x       = (const float*)d_in[0];
  const float* w_local = (const float*)d_in[1];
  const float* b_local = (const float*)d_in[2];
  const float* w_in    = (const float*)d_in[3];
  const float* b_in    = (const float*)d_in[4];
  const float* w_out   = (const float*)d_in[5];
  const float* b_out   = (const float*)d_in[6];
  const float* w_g2l   = (const float*)d_in[7];
  const float* b_g2l   = (const float*)d_in[8];
  const float* w_l2g   = (const float*)d_in[9];
  const float* b_l2g   = (const float*)d_in[10];
  const float* w_fu1   = (const float*)d_in[11];
  const float* b_fu1   = (const float*)d_in[12];
  const float* g_fu1   = (const float*)d_in[13];
  const float* be_fu1  = (const float*)d_in[14];
  const float* w_fu2   = (const float*)d_in[15];
  const float* b_fu2   = (const float*)d_in[16];
  const float* g_fu2   = (const float*)d_in[17];
  const float* be_fu2  = (const float*)d_in[18];
  float* out = (float*)d_out;

  // workspace layout (floats)
  float* ws   = (float*)d_ws;
  float* y_in = ws;                       // 8,388,608
  float* S1   = y_in + 8388608;           // 8,454,144 floats (spectral FU1; dead during bn_stats1)
  float* Z1   = S1 + 8454144;             // 8,454,144 (y_g overlays after Z1 dead)
  float* y_g  = Z1;
  float* S2   = Z1 + 8454144;             // 2,129,920 floats
  float* Z2   = S2 + 2129920;             // 2,129,920 (y2 overlays)
  float* y2   = Z2;
  float* st1  = Z2 + 2129920;             // scale[64], shift[64]
  float* st2  = st1 + 128;
  double* pb1 = (double*)S1;              // 64*32*2 doubles, overlaid on dead S1
  double* pb2 = (double*)S2;

  conv_in_v<<<1024, 256, 0, stream>>>(x, w_in, b_in, y_in);

  // ---- FU1 (256x256, Wf=129) ----
  rfft_rows<256, 8><<<32768, 128, 0, stream>>>(y_in, (float2*)S1);
  cfft_cols_t<256, 8, 16><<<128 * 9, 256, 0, stream>>>((float2*)S1, 129, -1.f, 9);
  conv_spec_v<4, 256, 129><<<516, 256, 0, stream>>>((const float4*)S1, w_fu1, b_fu1, (float2*)Z1);
  bn_stats_part<<<2048, 256, 0, stream>>>(Z1, 4128, pb1);
  bn_finalize<<<1, 64, 0, stream>>>(pb1, 132096, g_fu1, be_fu1, st1, st1 + 64);
  cfft_inv_bn<256, 8, 16><<<128 * 9, 256, 0, stream>>>(Z1, st1, st1 + 64, (float2*)S1, 129, 9, 132096);
  irfft_rows<256, 8><<<32768, 128, 0, stream>>>((const float2*)S1, y_g, 1.f / 65536.f);

  // ---- FU2 / LFU (128x128, Wf=65) ----
  rfft_rows_lfu<<<16384, 64, 0, stream>>>(y_in, (float2*)S2);
  cfft_cols_t<128, 7, 16><<<128 * 5, 256, 0, stream>>>((float2*)S2, 65, -1.f, 5);
  conv_spec_v<4, 128, 65><<<130, 256, 0, stream>>>((const float4*)S2, w_fu2, b_fu2, (float2*)Z2);
  bn_stats_part<<<2048, 256, 0, stream>>>(Z2, 1040, pb2);
  bn_finalize<<<1, 64, 0, stream>>>(pb2, 33280, g_fu2, be_fu2, st2, st2 + 64);
  cfft_inv_bn<128, 7, 16><<<128 * 5, 256, 0, stream>>>(Z2, st2, st2 + 64, (float2*)S2, 65, 5, 33280);
  irfft_rows<128, 7><<<16384, 64, 0, stream>>>((const float2*)S2, y2, 1.f / 16384.f);

  // ---- epilogues ----
  final_g_v<<<1024, 256, 0, stream>>>(x, y_g, y2, w_out, b_out, w_l2g, b_l2g, out);
  final_l_v<<<1024, 256, 0, stream>>>(x, w_local, b_local, w_g2l, b_g2l, out);
}